// Round 13
// baseline (77.797 us; speedup 1.0000x reference)
//
#include <hip/hip_runtime.h>

#define LOG2E 1.4426950408889634f

// B=4, C=64, HW=4096, HEADS=4, ch=16
// qsplit: bf16 [2][bh][i][ch16]  (plane 0 = hi, plane 1 = lo of f32 q*LOG2E)
// kT    : bf16 [bh][j][ch16] (32B rows)
// vb    : bf16 [b][o][hw]
// ao    : f32  [bh][i][ch16] == raw .view order [b][64][4096]

using s8v   = __attribute__((ext_vector_type(8))) short;
using u16x8 = __attribute__((ext_vector_type(8))) unsigned short;
using f32x4 = __attribute__((ext_vector_type(4))) float;

static __device__ __forceinline__ unsigned short bf16b(float f) {
  return __builtin_bit_cast(unsigned short, (__bf16)f);
}

// packed bf16 convert: dst = {lo: bf16(a), hi: bf16(b)}
static __device__ __forceinline__ unsigned cvtpk(float a, float b) {
  unsigned r;
  asm("v_cvt_pk_bf16_f32 %0, %1, %2" : "=v"(r) : "v"(a), "v"(b));
  return r;
}

__global__ __launch_bounds__(256) void qkv_proj(
    const float* __restrict__ x,
    const float* __restrict__ wq, const float* __restrict__ bq,
    const float* __restrict__ wk, const float* __restrict__ bk,
    const float* __restrict__ wv, const float* __restrict__ bv,
    unsigned short* __restrict__ qsplit, unsigned short* __restrict__ kT,
    unsigned short* __restrict__ vb) {
  __shared__ __align__(16) float xs[64][64];     // [c][px]
  __shared__ float wqs[64][65];                  // [c][o] transposed, padded
  __shared__ float wks[64][65];
  __shared__ float wvs[64][65];
  int t = threadIdx.x;
  int b = blockIdx.x >> 6;
  int px0 = (blockIdx.x & 63) << 6;
#pragma unroll
  for (int kk = 0; kk < 16; kk++) {
    int idx = kk * 256 + t;
    int c = idx >> 6, px = idx & 63;
    xs[c][px] = x[((size_t)(b * 64 + c) << 12) + px0 + px];
    int o = idx >> 6, c2 = idx & 63;
    wqs[c2][o] = wq[idx];
    wks[c2][o] = wk[idx];
    wvs[c2][o] = wv[idx];
  }
  __syncthreads();

  int o = t & 63;
  int pw = (t >> 6) << 4;
  float aq[16], ak[16], av[16];
#pragma unroll
  for (int p = 0; p < 16; p++) { aq[p] = 0.f; ak[p] = 0.f; av[p] = 0.f; }

  for (int c = 0; c < 64; c++) {
    float wqv = wqs[c][o], wkv = wks[c][o], wvv = wvs[c][o];
    float xr[16];
#pragma unroll
    for (int g = 0; g < 4; g++) {
      float4 x4 = *reinterpret_cast<const float4*>(&xs[c][pw + 4 * g]);
      xr[4 * g] = x4.x; xr[4 * g + 1] = x4.y; xr[4 * g + 2] = x4.z; xr[4 * g + 3] = x4.w;
    }
#pragma unroll
    for (int p = 0; p < 16; p++) {
      aq[p] += wqv * xr[p];
      ak[p] += wkv * xr[p];
      av[p] += wvv * xr[p];
    }
  }

  float bqv = bq[o], bkv = bk[o], bvv = bv[o];
  {
    // v: bf16 [b][o][hw]
    unsigned short* dstv = vb + ((size_t)(b * 64 + o) << 12) + px0 + pw;
    u16x8 v0, v1;
#pragma unroll
    for (int p = 0; p < 8; p++) {
      v0[p] = bf16b(av[p] + bvv);
      v1[p] = bf16b(av[8 + p] + bvv);
    }
    *reinterpret_cast<u16x8*>(dstv) = v0;
    *reinterpret_cast<u16x8*>(dstv + 8) = v1;
  }
  // q hi/lo planes + k, all bf16 [bh][j/i][ch]
  int bh = b * 4 + (o >> 4);
  int chn = o & 15;
  size_t kb = ((size_t)bh << 16) + ((size_t)(px0 + pw) << 4) + chn;
#pragma unroll
  for (int p = 0; p < 16; p++) {
    float f = (aq[p] + bqv) * LOG2E;
    __bf16 hi = (__bf16)f;
    qsplit[kb + ((size_t)p << 4)] = __builtin_bit_cast(unsigned short, hi);
    qsplit[kb + ((size_t)p << 4) + (1u << 20)] = bf16b(f - (float)hi);
    kT[kb + ((size_t)p << 4)] = bf16b(ak[p] + bkv);
  }
}

// MFMA flash attention, no max tracking (scores bounded; fixed-M softmax is
// exact in f32 range). grid = 1024 (16 bh x 64 i-tiles of 64 queries), block =
// 4 waves; wave w owns j-slice [w*1024, +1024), 64 j per iteration.
// SPLIT ACCUMULATORS: accA/accB (and acclA/acclB) per 32-j group break the
// PV mfma->mfma result-latency chains the compiler cannot reorder (FP sum
// order); merged by 8 VALU adds in the epilogue. One-g QK lookahead decouples
// exp(g) from QK(g) mfma latency.
// Swapped QK^T: S^T = mfma(Kdup, [Qhi|Qlo]) -> lane(i_,q4) holds
// s0[r]=S[jb+4q4+r][i_], s1[r]=S[jb+16+4q4+r][i_].
// PV k-slot perm perm(8q4+e)= e<4 ? 4q4+e : 16+4q4+e-4 on BOTH V-A and P-B
// fragments -> P B-frag is the lane's own exp values; zero cross-lane traffic.
// l via ones-MFMA (idle matrix pipe); P packing via v_cvt_pk_bf16_f32.
__global__ __launch_bounds__(256) void attn_mfma(
    const unsigned short* __restrict__ qsplit,
    const unsigned short* __restrict__ kT,
    const unsigned short* __restrict__ vb, float* __restrict__ ao) {
  __shared__ float red[4][64][18];
  const int tid  = threadIdx.x;
  const int w    = tid >> 6;
  const int lane = tid & 63;
  const int i_   = lane & 15;
  const int q4   = lane >> 4;
  const int chb  = (q4 & 1) << 3;

  // XCD swizzle: 2 bh per XCD
  const int orig = ((blockIdx.x & 7) << 7) + (blockIdx.x >> 3);
  const int bh = orig >> 6;
  const int i0 = (orig & 63) << 6;
  const int b = bh >> 2, h = bh & 3;

  // Q B-frags: lane col n=i_, k=8q4+e; k<16 -> Qhi plane, k>=16 -> Qlo plane,
  // channel chb+e. One 16B load per g.
  const unsigned short* qpb =
      qsplit + ((size_t)(q4 >> 1) << 20) + ((size_t)bh << 16) + chb;
  s8v BQ[4];
#pragma unroll
  for (int g = 0; g < 4; ++g) {
    BQ[g] = *(const s8v*)(qpb + ((size_t)(i0 + (g << 4) + i_) << 4));
  }

  s8v ones;
#pragma unroll
  for (int e = 0; e < 8; ++e) ones[e] = (short)0x3F80;  // bf16 1.0

  f32x4 accA[4], accB[4], acclA[4], acclB[4];
#pragma unroll
  for (int g = 0; g < 4; ++g) {
    accA[g] = (f32x4){0.f, 0.f, 0.f, 0.f};
    accB[g] = (f32x4){0.f, 0.f, 0.f, 0.f};
    acclA[g] = (f32x4){0.f, 0.f, 0.f, 0.f};
    acclB[g] = (f32x4){0.f, 0.f, 0.f, 0.f};
  }

  const unsigned short* vpb = vb + (((size_t)(b * 64 + h * 16 + i_)) << 12);
  const unsigned short* kpb = kT + ((size_t)bh << 16);

  for (int t = 0; t < 16; ++t) {
    const int ja = (w << 10) + (t << 6);
    const int jbB = ja + 32;
    s8v AVa, AVb;
    {
      struct { uint2 a, b; } pa, pb;
      pa.a = *(const uint2*)(vpb + ja + (q4 << 2));
      pa.b = *(const uint2*)(vpb + ja + 16 + (q4 << 2));
      pb.a = *(const uint2*)(vpb + jbB + (q4 << 2));
      pb.b = *(const uint2*)(vpb + jbB + 16 + (q4 << 2));
      AVa = __builtin_bit_cast(s8v, pa);
      AVb = __builtin_bit_cast(s8v, pb);
    }
    s8v AK0a = *(const s8v*)(kpb + (((size_t)(ja + i_)) << 4) + chb);
    s8v AK1a = *(const s8v*)(kpb + (((size_t)(ja + 16 + i_)) << 4) + chb);
    s8v AK0b = *(const s8v*)(kpb + (((size_t)(jbB + i_)) << 4) + chb);
    s8v AK1b = *(const s8v*)(kpb + (((size_t)(jbB + 16 + i_)) << 4) + chb);

    const f32x4 z = {0.f, 0.f, 0.f, 0.f};
    // QK lookahead: scores for g=0
    f32x4 sn0 = __builtin_amdgcn_mfma_f32_16x16x32_bf16(AK0a, BQ[0], z, 0, 0, 0);
    f32x4 sn1 = __builtin_amdgcn_mfma_f32_16x16x32_bf16(AK1a, BQ[0], z, 0, 0, 0);
    f32x4 sn2 = __builtin_amdgcn_mfma_f32_16x16x32_bf16(AK0b, BQ[0], z, 0, 0, 0);
    f32x4 sn3 = __builtin_amdgcn_mfma_f32_16x16x32_bf16(AK1b, BQ[0], z, 0, 0, 0);

#pragma unroll
    for (int g = 0; g < 4; ++g) {
      f32x4 s0 = sn0, s1 = sn1, s2 = sn2, s3 = sn3;
      if (g < 3) {
        sn0 = __builtin_amdgcn_mfma_f32_16x16x32_bf16(AK0a, BQ[g + 1], z, 0, 0, 0);
        sn1 = __builtin_amdgcn_mfma_f32_16x16x32_bf16(AK1a, BQ[g + 1], z, 0, 0, 0);
        sn2 = __builtin_amdgcn_mfma_f32_16x16x32_bf16(AK0b, BQ[g + 1], z, 0, 0, 0);
        sn3 = __builtin_amdgcn_mfma_f32_16x16x32_bf16(AK1b, BQ[g + 1], z, 0, 0, 0);
      }
      float pa0 = __builtin_amdgcn_exp2f(s0[0]);
      float pa1 = __builtin_amdgcn_exp2f(s0[1]);
      float pa2 = __builtin_amdgcn_exp2f(s0[2]);
      float pa3 = __builtin_amdgcn_exp2f(s0[3]);
      float pa4 = __builtin_amdgcn_exp2f(s1[0]);
      float pa5 = __builtin_amdgcn_exp2f(s1[1]);
      float pa6 = __builtin_amdgcn_exp2f(s1[2]);
      float pa7 = __builtin_amdgcn_exp2f(s1[3]);
      float pb0 = __builtin_amdgcn_exp2f(s2[0]);
      float pb1 = __builtin_amdgcn_exp2f(s2[1]);
      float pb2 = __builtin_amdgcn_exp2f(s2[2]);
      float pb3 = __builtin_amdgcn_exp2f(s2[3]);
      float pb4 = __builtin_amdgcn_exp2f(s3[0]);
      float pb5 = __builtin_amdgcn_exp2f(s3[1]);
      float pb6 = __builtin_amdgcn_exp2f(s3[2]);
      float pb7 = __builtin_amdgcn_exp2f(s3[3]);
      struct { unsigned x, y, z, w; } ua, ub;
      ua.x = cvtpk(pa0, pa1); ua.y = cvtpk(pa2, pa3);
      ua.z = cvtpk(pa4, pa5); ua.w = cvtpk(pa6, pa7);
      ub.x = cvtpk(pb0, pb1); ub.y = cvtpk(pb2, pb3);
      ub.z = cvtpk(pb4, pb5); ub.w = cvtpk(pb6, pb7);
      s8v PA = __builtin_bit_cast(s8v, ua);
      s8v PB = __builtin_bit_cast(s8v, ub);
      // independent accumulator chains per j-group
      accA[g]  = __builtin_amdgcn_mfma_f32_16x16x32_bf16(AVa, PA, accA[g], 0, 0, 0);
      accB[g]  = __builtin_amdgcn_mfma_f32_16x16x32_bf16(AVb, PB, accB[g], 0, 0, 0);
      acclA[g] = __builtin_amdgcn_mfma_f32_16x16x32_bf16(ones, PA, acclA[g], 0, 0, 0);
      acclB[g] = __builtin_amdgcn_mfma_f32_16x16x32_bf16(ones, PB, acclB[g], 0, 0, 0);
    }
  }

  // per-wave results -> LDS merge across the 4 j-slices (pure sums;
  // accl[g][0] is the per-query l, identical on all 4 lanes of a query)
#pragma unroll
  for (int g = 0; g < 4; ++g) {
    int iq = (g << 4) + i_;
    if (q4 == 0) red[w][iq][0] = acclA[g][0] + acclB[g][0];
    red[w][iq][1 + (q4 << 2) + 0] = accA[g][0] + accB[g][0];
    red[w][iq][1 + (q4 << 2) + 1] = accA[g][1] + accB[g][1];
    red[w][iq][1 + (q4 << 2) + 2] = accA[g][2] + accB[g][2];
    red[w][iq][1 + (q4 << 2) + 3] = accA[g][3] + accB[g][3];
  }
  __syncthreads();

  {
    int iq = tid & 63, quad = tid >> 6;
    float L = (red[0][iq][0] + red[1][iq][0]) + (red[2][iq][0] + red[3][iq][0]);
    float o0 = 0.f, o1 = 0.f, o2 = 0.f, o3 = 0.f;
#pragma unroll
    for (int s = 0; s < 4; ++s) {
      o0 += red[s][iq][1 + (quad << 2) + 0];
      o1 += red[s][iq][1 + (quad << 2) + 1];
      o2 += red[s][iq][1 + (quad << 2) + 2];
      o3 += red[s][iq][1 + (quad << 2) + 3];
    }
    float inv = 1.0f / L;
    float4 o = { o0 * inv, o1 * inv, o2 * inv, o3 * inv };
    *(float4*)&ao[((((size_t)bh << 12) + i0 + iq) << 4) + (quad << 2)] = o;
  }
}

__global__ __launch_bounds__(256) void out_proj(
    const float* __restrict__ a, const float* __restrict__ wp,
    const float* __restrict__ bp, float* __restrict__ out) {
  __shared__ __align__(16) float as[64][64];
  __shared__ float wps[64][65];
  int t = threadIdx.x;
  int b = blockIdx.x >> 6;
  int px0 = (blockIdx.x & 63) << 6;
#pragma unroll
  for (int kk = 0; kk < 16; kk++) {
    int idx = kk * 256 + t;
    int c = idx >> 6, px = idx & 63;
    as[c][px] = a[((size_t)b << 18) + ((size_t)c << 12) + px0 + px];
    int o = idx >> 6, c2 = idx & 63;
    wps[c2][o] = wp[idx];
  }
  __syncthreads();

  int o = t & 63;
  int pw = (t >> 6) << 4;
  float acc[16];
#pragma unroll
  for (int p = 0; p < 16; p++) acc[p] = 0.f;
  for (int c = 0; c < 64; c++) {
    float wv = wps[c][o];
    float xr[16];
#pragma unroll
    for (int g = 0; g < 4; g++) {
      float4 x4 = *reinterpret_cast<const float4*>(&as[c][pw + 4 * g]);
      xr[4 * g] = x4.x; xr[4 * g + 1] = x4.y; xr[4 * g + 2] = x4.z; xr[4 * g + 3] = x4.w;
    }
#pragma unroll
    for (int p = 0; p < 16; p++) acc[p] += wv * xr[p];
  }
  float bv = bp[o];
  float* dst = out + ((size_t)(b * 64 + o) << 12) + px0 + pw;
#pragma unroll
  for (int g = 0; g < 4; g++) {
    float4 v4 = { acc[4 * g + 0] + bv, acc[4 * g + 1] + bv,
                  acc[4 * g + 2] + bv, acc[4 * g + 3] + bv };
    reinterpret_cast<float4*>(dst)[g] = v4;
  }
}

extern "C" void kernel_launch(void* const* d_in, const int* in_sizes, int n_in,
                              void* d_out, int out_size, void* d_ws, size_t ws_size,
                              hipStream_t stream) {
  (void)in_sizes; (void)n_in; (void)out_size; (void)ws_size;
  const float* x  = (const float*)d_in[0];
  const float* wq = (const float*)d_in[1];
  const float* bq = (const float*)d_in[2];
  const float* wk = (const float*)d_in[3];
  const float* bk = (const float*)d_in[4];
  const float* wv = (const float*)d_in[5];
  const float* bv = (const float*)d_in[6];
  const float* wp = (const float*)d_in[7];
  const float* bp = (const float*)d_in[8];

  char* ws = (char*)d_ws;
  unsigned short* qsplit = (unsigned short*)ws;              // 4MB (hi+lo planes)
  unsigned short* kT = (unsigned short*)(ws + (4u << 20));   // 2MB bf16
  unsigned short* vT = (unsigned short*)(ws + (6u << 20));   // 2MB bf16
  float* ao = (float*)(ws + (8u << 20));                     // 4MB f32

  qkv_proj<<<256, 256, 0, stream>>>(x, wq, bq, wk, bk, wv, bv, qsplit, kT, vT);
  attn_mfma<<<1024, 256, 0, stream>>>(qsplit, kT, vT, ao);
  out_proj<<<256, 256, 0, stream>>>(ao, wp, bp, (float*)d_out);
}

// Round 14
// 71.525 us; speedup vs baseline: 1.0877x; 1.0877x over previous
//
#include <hip/hip_runtime.h>

#define LOG2E 1.4426950408889634f

// B=4, C=64, HW=4096, HEADS=4, ch=16
// qsplit: bf16 [2][bh][i][ch16]  (plane 0 = hi, plane 1 = lo of f32 q*LOG2E)
// kT    : bf16 [bh][j][ch16] (32B rows)
// vb    : bf16 [b][o][hw]
// ao    : f32  [bh][i][ch16] == raw .view order [b][64][4096]

using s8v   = __attribute__((ext_vector_type(8))) short;
using u16x8 = __attribute__((ext_vector_type(8))) unsigned short;
using f32x4 = __attribute__((ext_vector_type(4))) float;

static __device__ __forceinline__ unsigned short bf16b(float f) {
  return __builtin_bit_cast(unsigned short, (__bf16)f);
}

// packed bf16 convert: dst = {lo: bf16(a), hi: bf16(b)}
static __device__ __forceinline__ unsigned cvtpk(float a, float b) {
  unsigned r;
  asm("v_cvt_pk_bf16_f32 %0, %1, %2" : "=v"(r) : "v"(a), "v"(b));
  return r;
}

__global__ __launch_bounds__(256) void qkv_proj(
    const float* __restrict__ x,
    const float* __restrict__ wq, const float* __restrict__ bq,
    const float* __restrict__ wk, const float* __restrict__ bk,
    const float* __restrict__ wv, const float* __restrict__ bv,
    unsigned short* __restrict__ qsplit, unsigned short* __restrict__ kT,
    unsigned short* __restrict__ vb) {
  __shared__ __align__(16) float xs[64][64];     // [c][px]
  __shared__ float wqs[64][65];                  // [c][o] transposed, padded
  __shared__ float wks[64][65];
  __shared__ float wvs[64][65];
  int t = threadIdx.x;
  int b = blockIdx.x >> 6;
  int px0 = (blockIdx.x & 63) << 6;
#pragma unroll
  for (int kk = 0; kk < 16; kk++) {
    int idx = kk * 256 + t;
    int c = idx >> 6, px = idx & 63;
    xs[c][px] = x[((size_t)(b * 64 + c) << 12) + px0 + px];
    int o = idx >> 6, c2 = idx & 63;
    wqs[c2][o] = wq[idx];
    wks[c2][o] = wk[idx];
    wvs[c2][o] = wv[idx];
  }
  __syncthreads();

  int o = t & 63;
  int pw = (t >> 6) << 4;
  float aq[16], ak[16], av[16];
#pragma unroll
  for (int p = 0; p < 16; p++) { aq[p] = 0.f; ak[p] = 0.f; av[p] = 0.f; }

  for (int c = 0; c < 64; c++) {
    float wqv = wqs[c][o], wkv = wks[c][o], wvv = wvs[c][o];
    float xr[16];
#pragma unroll
    for (int g = 0; g < 4; g++) {
      float4 x4 = *reinterpret_cast<const float4*>(&xs[c][pw + 4 * g]);
      xr[4 * g] = x4.x; xr[4 * g + 1] = x4.y; xr[4 * g + 2] = x4.z; xr[4 * g + 3] = x4.w;
    }
#pragma unroll
    for (int p = 0; p < 16; p++) {
      aq[p] += wqv * xr[p];
      ak[p] += wkv * xr[p];
      av[p] += wvv * xr[p];
    }
  }

  float bqv = bq[o], bkv = bk[o], bvv = bv[o];
  {
    // v: bf16 [b][o][hw]
    unsigned short* dstv = vb + ((size_t)(b * 64 + o) << 12) + px0 + pw;
    u16x8 v0, v1;
#pragma unroll
    for (int p = 0; p < 8; p++) {
      v0[p] = bf16b(av[p] + bvv);
      v1[p] = bf16b(av[8 + p] + bvv);
    }
    *reinterpret_cast<u16x8*>(dstv) = v0;
    *reinterpret_cast<u16x8*>(dstv + 8) = v1;
  }
  // q hi/lo planes + k, all bf16 [bh][j/i][ch]
  int bh = b * 4 + (o >> 4);
  int chn = o & 15;
  size_t kb = ((size_t)bh << 16) + ((size_t)(px0 + pw) << 4) + chn;
#pragma unroll
  for (int p = 0; p < 16; p++) {
    float f = (aq[p] + bqv) * LOG2E;
    __bf16 hi = (__bf16)f;
    qsplit[kb + ((size_t)p << 4)] = __builtin_bit_cast(unsigned short, hi);
    qsplit[kb + ((size_t)p << 4) + (1u << 20)] = bf16b(f - (float)hi);
    kT[kb + ((size_t)p << 4)] = bf16b(ak[p] + bkv);
  }
}

// MFMA flash attention, no max tracking (scores bounded; fixed-M softmax is
// exact in f32 range). grid = 1024 (16 bh x 64 i-tiles of 64 queries), block =
// 4 waves; wave w owns j-slice [w*1024, +1024), 64 j per iteration (two
// independent 32-j groups for ILP). R11 structure (best measured); R12
// prefetch / R13 split-acc+lookahead both regressed (register pressure beats
// dependency-breaking in this balance).
// s_setprio(1) around each g's MFMA cluster (T5): waves in a block run the
// loop barrier-free and drift into different phases -> priority lets the
// MFMA-issuing wave win arbitration while others are in exp/pack phase.
// Swapped QK^T: S^T = mfma(Kdup, [Qhi|Qlo]) -> lane(i_,q4) holds
// s0[r]=S[jb+4q4+r][i_], s1[r]=S[jb+16+4q4+r][i_].
// PV k-slot perm perm(8q4+e)= e<4 ? 4q4+e : 16+4q4+e-4 on BOTH V-A and P-B
// fragments -> P B-frag is the lane's own exp values; zero cross-lane traffic.
// l via ones-MFMA (idle matrix pipe); P packing via v_cvt_pk_bf16_f32.
__global__ __launch_bounds__(256) void attn_mfma(
    const unsigned short* __restrict__ qsplit,
    const unsigned short* __restrict__ kT,
    const unsigned short* __restrict__ vb, float* __restrict__ ao) {
  __shared__ float red[4][64][20];   // padded rows (18->20) vs epilogue conflicts
  const int tid  = threadIdx.x;
  const int w    = tid >> 6;
  const int lane = tid & 63;
  const int i_   = lane & 15;
  const int q4   = lane >> 4;
  const int chb  = (q4 & 1) << 3;

  // XCD swizzle: 2 bh per XCD
  const int orig = ((blockIdx.x & 7) << 7) + (blockIdx.x >> 3);
  const int bh = orig >> 6;
  const int i0 = (orig & 63) << 6;
  const int b = bh >> 2, h = bh & 3;

  // Q B-frags: lane col n=i_, k=8q4+e; k<16 -> Qhi plane, k>=16 -> Qlo plane,
  // channel chb+e. One 16B load per g.
  const unsigned short* qpb =
      qsplit + ((size_t)(q4 >> 1) << 20) + ((size_t)bh << 16) + chb;
  s8v BQ[4];
#pragma unroll
  for (int g = 0; g < 4; ++g) {
    BQ[g] = *(const s8v*)(qpb + ((size_t)(i0 + (g << 4) + i_) << 4));
  }

  s8v ones;
#pragma unroll
  for (int e = 0; e < 8; ++e) ones[e] = (short)0x3F80;  // bf16 1.0

  f32x4 acc[4], accl[4];
#pragma unroll
  for (int g = 0; g < 4; ++g) {
    acc[g] = (f32x4){0.f, 0.f, 0.f, 0.f};
    accl[g] = (f32x4){0.f, 0.f, 0.f, 0.f};
  }

  const unsigned short* vpb = vb + (((size_t)(b * 64 + h * 16 + i_)) << 12);
  const unsigned short* kpb = kT + ((size_t)bh << 16);

  for (int t = 0; t < 16; ++t) {
    const int ja = (w << 10) + (t << 6);
    const int jbB = ja + 32;
    // Two independent 32-j load groups (A at ja, B at ja+32)
    s8v AVa, AVb;
    {
      struct { uint2 a, b; } pa, pb;
      pa.a = *(const uint2*)(vpb + ja + (q4 << 2));
      pa.b = *(const uint2*)(vpb + ja + 16 + (q4 << 2));
      pb.a = *(const uint2*)(vpb + jbB + (q4 << 2));
      pb.b = *(const uint2*)(vpb + jbB + 16 + (q4 << 2));
      AVa = __builtin_bit_cast(s8v, pa);
      AVb = __builtin_bit_cast(s8v, pb);
    }
    s8v AK0a = *(const s8v*)(kpb + (((size_t)(ja + i_)) << 4) + chb);
    s8v AK1a = *(const s8v*)(kpb + (((size_t)(ja + 16 + i_)) << 4) + chb);
    s8v AK0b = *(const s8v*)(kpb + (((size_t)(jbB + i_)) << 4) + chb);
    s8v AK1b = *(const s8v*)(kpb + (((size_t)(jbB + 16 + i_)) << 4) + chb);

#pragma unroll
    for (int g = 0; g < 4; ++g) {
      f32x4 z = {0.f, 0.f, 0.f, 0.f};
      __builtin_amdgcn_s_setprio(1);
      f32x4 s0 = __builtin_amdgcn_mfma_f32_16x16x32_bf16(AK0a, BQ[g], z, 0, 0, 0);
      f32x4 s1 = __builtin_amdgcn_mfma_f32_16x16x32_bf16(AK1a, BQ[g], z, 0, 0, 0);
      f32x4 s2 = __builtin_amdgcn_mfma_f32_16x16x32_bf16(AK0b, BQ[g], z, 0, 0, 0);
      f32x4 s3 = __builtin_amdgcn_mfma_f32_16x16x32_bf16(AK1b, BQ[g], z, 0, 0, 0);
      __builtin_amdgcn_s_setprio(0);
      float pa0 = __builtin_amdgcn_exp2f(s0[0]);
      float pa1 = __builtin_amdgcn_exp2f(s0[1]);
      float pa2 = __builtin_amdgcn_exp2f(s0[2]);
      float pa3 = __builtin_amdgcn_exp2f(s0[3]);
      float pa4 = __builtin_amdgcn_exp2f(s1[0]);
      float pa5 = __builtin_amdgcn_exp2f(s1[1]);
      float pa6 = __builtin_amdgcn_exp2f(s1[2]);
      float pa7 = __builtin_amdgcn_exp2f(s1[3]);
      float pb0 = __builtin_amdgcn_exp2f(s2[0]);
      float pb1 = __builtin_amdgcn_exp2f(s2[1]);
      float pb2 = __builtin_amdgcn_exp2f(s2[2]);
      float pb3 = __builtin_amdgcn_exp2f(s2[3]);
      float pb4 = __builtin_amdgcn_exp2f(s3[0]);
      float pb5 = __builtin_amdgcn_exp2f(s3[1]);
      float pb6 = __builtin_amdgcn_exp2f(s3[2]);
      float pb7 = __builtin_amdgcn_exp2f(s3[3]);
      struct { unsigned x, y, z, w; } ua, ub;
      ua.x = cvtpk(pa0, pa1); ua.y = cvtpk(pa2, pa3);
      ua.z = cvtpk(pa4, pa5); ua.w = cvtpk(pa6, pa7);
      ub.x = cvtpk(pb0, pb1); ub.y = cvtpk(pb2, pb3);
      ub.z = cvtpk(pb4, pb5); ub.w = cvtpk(pb6, pb7);
      s8v PA = __builtin_bit_cast(s8v, ua);
      s8v PB = __builtin_bit_cast(s8v, ub);
      __builtin_amdgcn_s_setprio(1);
      acc[g]  = __builtin_amdgcn_mfma_f32_16x16x32_bf16(AVa, PA, acc[g], 0, 0, 0);
      acc[g]  = __builtin_amdgcn_mfma_f32_16x16x32_bf16(AVb, PB, acc[g], 0, 0, 0);
      accl[g] = __builtin_amdgcn_mfma_f32_16x16x32_bf16(ones, PA, accl[g], 0, 0, 0);
      accl[g] = __builtin_amdgcn_mfma_f32_16x16x32_bf16(ones, PB, accl[g], 0, 0, 0);
      __builtin_amdgcn_s_setprio(0);
    }
  }

  // per-wave results -> LDS merge across the 4 j-slices (pure sums;
  // accl[g][0] is the per-query l, identical on all 4 lanes of a query)
#pragma unroll
  for (int g = 0; g < 4; ++g) {
    int iq = (g << 4) + i_;
    if (q4 == 0) red[w][iq][0] = accl[g][0];
    red[w][iq][1 + (q4 << 2) + 0] = acc[g][0];
    red[w][iq][1 + (q4 << 2) + 1] = acc[g][1];
    red[w][iq][1 + (q4 << 2) + 2] = acc[g][2];
    red[w][iq][1 + (q4 << 2) + 3] = acc[g][3];
  }
  __syncthreads();

  {
    int iq = tid & 63, quad = tid >> 6;
    float L = (red[0][iq][0] + red[1][iq][0]) + (red[2][iq][0] + red[3][iq][0]);
    float o0 = 0.f, o1 = 0.f, o2 = 0.f, o3 = 0.f;
#pragma unroll
    for (int s = 0; s < 4; ++s) {
      o0 += red[s][iq][1 + (quad << 2) + 0];
      o1 += red[s][iq][1 + (quad << 2) + 1];
      o2 += red[s][iq][1 + (quad << 2) + 2];
      o3 += red[s][iq][1 + (quad << 2) + 3];
    }
    float inv = 1.0f / L;
    float4 o = { o0 * inv, o1 * inv, o2 * inv, o3 * inv };
    *(float4*)&ao[((((size_t)bh << 12) + i0 + iq) << 4) + (quad << 2)] = o;
  }
}

__global__ __launch_bounds__(256) void out_proj(
    const float* __restrict__ a, const float* __restrict__ wp,
    const float* __restrict__ bp, float* __restrict__ out) {
  __shared__ __align__(16) float as[64][64];
  __shared__ float wps[64][65];
  int t = threadIdx.x;
  int b = blockIdx.x >> 6;
  int px0 = (blockIdx.x & 63) << 6;
#pragma unroll
  for (int kk = 0; kk < 16; kk++) {
    int idx = kk * 256 + t;
    int c = idx >> 6, px = idx & 63;
    as[c][px] = a[((size_t)b << 18) + ((size_t)c << 12) + px0 + px];
    int o = idx >> 6, c2 = idx & 63;
    wps[c2][o] = wp[idx];
  }
  __syncthreads();

  int o = t & 63;
  int pw = (t >> 6) << 4;
  float acc[16];
#pragma unroll
  for (int p = 0; p < 16; p++) acc[p] = 0.f;
  for (int c = 0; c < 64; c++) {
    float wv = wps[c][o];
    float xr[16];
#pragma unroll
    for (int g = 0; g < 4; g++) {
      float4 x4 = *reinterpret_cast<const float4*>(&as[c][pw + 4 * g]);
      xr[4 * g] = x4.x; xr[4 * g + 1] = x4.y; xr[4 * g + 2] = x4.z; xr[4 * g + 3] = x4.w;
    }
#pragma unroll
    for (int p = 0; p < 16; p++) acc[p] += wv * xr[p];
  }
  float bv = bp[o];
  float* dst = out + ((size_t)(b * 64 + o) << 12) + px0 + pw;
#pragma unroll
  for (int g = 0; g < 4; g++) {
    float4 v4 = { acc[4 * g + 0] + bv, acc[4 * g + 1] + bv,
                  acc[4 * g + 2] + bv, acc[4 * g + 3] + bv };
    reinterpret_cast<float4*>(dst)[g] = v4;
  }
}

extern "C" void kernel_launch(void* const* d_in, const int* in_sizes, int n_in,
                              void* d_out, int out_size, void* d_ws, size_t ws_size,
                              hipStream_t stream) {
  (void)in_sizes; (void)n_in; (void)out_size; (void)ws_size;
  const float* x  = (const float*)d_in[0];
  const float* wq = (const float*)d_in[1];
  const float* bq = (const float*)d_in[2];
  const float* wk = (const float*)d_in[3];
  const float* bk = (const float*)d_in[4];
  const float* wv = (const float*)d_in[5];
  const float* bv = (const float*)d_in[6];
  const float* wp = (const float*)d_in[7];
  const float* bp = (const float*)d_in[8];

  char* ws = (char*)d_ws;
  unsigned short* qsplit = (unsigned short*)ws;              // 4MB (hi+lo planes)
  unsigned short* kT = (unsigned short*)(ws + (4u << 20));   // 2MB bf16
  unsigned short* vT = (unsigned short*)(ws + (6u << 20));   // 2MB bf16
  float* ao = (float*)(ws + (8u << 20));                     // 4MB f32

  qkv_proj<<<256, 256, 0, stream>>>(x, wq, bq, wk, bk, wv, bv, qsplit, kT, vT);
  attn_mfma<<<1024, 256, 0, stream>>>(qsplit, kT, vT, ao);
  out_proj<<<256, 256, 0, stream>>>(ao, wp, bp, (float*)d_out);
}

// Round 15
// 67.649 us; speedup vs baseline: 1.1500x; 1.0573x over previous
//
#include <hip/hip_runtime.h>

#define LOG2E 1.4426950408889634f

// B=4, C=64, HW=4096, HEADS=4, ch=16
// qsplit: bf16 [2][bh][i][ch16]  (plane 0 = hi, plane 1 = lo of f32 q*LOG2E)
// kT    : bf16 [bh][j][ch16] (32B rows)
// vb    : bf16 [b][o][hw]
// ao    : f32  [bh][i][ch16] == raw .view order [b][64][4096]

using s8v   = __attribute__((ext_vector_type(8))) short;
using u16x8 = __attribute__((ext_vector_type(8))) unsigned short;
using f32x4 = __attribute__((ext_vector_type(4))) float;

static __device__ __forceinline__ unsigned short bf16b(float f) {
  return __builtin_bit_cast(unsigned short, (__bf16)f);
}

// packed bf16 convert: dst = {lo: bf16(a), hi: bf16(b)}
static __device__ __forceinline__ unsigned cvtpk(float a, float b) {
  unsigned r;
  asm("v_cvt_pk_bf16_f32 %0, %1, %2" : "=v"(r) : "v"(a), "v"(b));
  return r;
}

// 32-pixel tiles -> grid 512 -> 2 blocks/CU (LDS 58KB/block), 8 waves/SIMD
// (was 256 blocks = 1 block/CU, occupancy-starved by grid).
__global__ __launch_bounds__(256) void qkv_proj(
    const float* __restrict__ x,
    const float* __restrict__ wq, const float* __restrict__ bq,
    const float* __restrict__ wk, const float* __restrict__ bk,
    const float* __restrict__ wv, const float* __restrict__ bv,
    unsigned short* __restrict__ qsplit, unsigned short* __restrict__ kT,
    unsigned short* __restrict__ vb) {
  __shared__ __align__(16) float xs[64][32];     // [c][px]
  __shared__ float wqs[64][65];                  // [c][o] transposed, padded
  __shared__ float wks[64][65];
  __shared__ float wvs[64][65];
  int t = threadIdx.x;
  int b = blockIdx.x >> 7;                // 128 tiles per batch
  int px0 = (blockIdx.x & 127) << 5;
#pragma unroll
  for (int kk = 0; kk < 16; kk++) {
    int idx = kk * 256 + t;               // idx = o*64 + c
    int o = idx >> 6, c2 = idx & 63;
    wqs[c2][o] = wq[idx];
    wks[c2][o] = wk[idx];
    wvs[c2][o] = wv[idx];
  }
#pragma unroll
  for (int kk = 0; kk < 8; kk++) {
    int idx = kk * 256 + t;
    int c = idx >> 5, px = idx & 31;
    xs[c][px] = x[((size_t)(b * 64 + c) << 12) + px0 + px];
  }
  __syncthreads();

  int o = t & 63;
  int pw = (t >> 6) << 3;                 // 8-pixel sub-tile
  float aq[8], ak[8], av[8];
#pragma unroll
  for (int p = 0; p < 8; p++) { aq[p] = 0.f; ak[p] = 0.f; av[p] = 0.f; }

  for (int c = 0; c < 64; c++) {
    float wqv = wqs[c][o], wkv = wks[c][o], wvv = wvs[c][o];
    float4 x0 = *reinterpret_cast<const float4*>(&xs[c][pw]);
    float4 x1 = *reinterpret_cast<const float4*>(&xs[c][pw + 4]);
    float xr[8] = { x0.x, x0.y, x0.z, x0.w, x1.x, x1.y, x1.z, x1.w };
#pragma unroll
    for (int p = 0; p < 8; p++) {
      aq[p] += wqv * xr[p];
      ak[p] += wkv * xr[p];
      av[p] += wvv * xr[p];
    }
  }

  float bqv = bq[o], bkv = bk[o], bvv = bv[o];
  {
    // v: bf16 [b][o][hw]
    unsigned short* dstv = vb + ((size_t)(b * 64 + o) << 12) + px0 + pw;
    u16x8 v0;
#pragma unroll
    for (int p = 0; p < 8; p++) v0[p] = bf16b(av[p] + bvv);
    *reinterpret_cast<u16x8*>(dstv) = v0;
  }
  // q hi/lo planes + k, all bf16 [bh][j/i][ch]
  int bh = b * 4 + (o >> 4);
  int chn = o & 15;
  size_t kb = ((size_t)bh << 16) + ((size_t)(px0 + pw) << 4) + chn;
#pragma unroll
  for (int p = 0; p < 8; p++) {
    float f = (aq[p] + bqv) * LOG2E;
    __bf16 hi = (__bf16)f;
    qsplit[kb + ((size_t)p << 4)] = __builtin_bit_cast(unsigned short, hi);
    qsplit[kb + ((size_t)p << 4) + (1u << 20)] = bf16b(f - (float)hi);
    kT[kb + ((size_t)p << 4)] = bf16b(ak[p] + bkv);
  }
}

// MFMA flash attention, no max tracking (scores bounded; fixed-M softmax is
// exact in f32 range). grid = 1024 (16 bh x 64 i-tiles of 64 queries), block =
// 4 waves; wave w owns j-slice [w*1024, +1024), 64 j per iteration (two
// independent 32-j groups for ILP). Exact R11 structure -- best measured;
// R12 prefetch / R13 split-acc / R14 setprio+pad all regressed.
// Swapped QK^T: S^T = mfma(Kdup, [Qhi|Qlo]) -> lane(i_,q4) holds
// s0[r]=S[jb+4q4+r][i_], s1[r]=S[jb+16+4q4+r][i_].
// PV k-slot perm perm(8q4+e)= e<4 ? 4q4+e : 16+4q4+e-4 on BOTH V-A and P-B
// fragments -> P B-frag is the lane's own exp values; zero cross-lane traffic.
// l via ones-MFMA (idle matrix pipe); P packing via v_cvt_pk_bf16_f32.
__global__ __launch_bounds__(256) void attn_mfma(
    const unsigned short* __restrict__ qsplit,
    const unsigned short* __restrict__ kT,
    const unsigned short* __restrict__ vb, float* __restrict__ ao) {
  __shared__ float red[4][64][18];
  const int tid  = threadIdx.x;
  const int w    = tid >> 6;
  const int lane = tid & 63;
  const int i_   = lane & 15;
  const int q4   = lane >> 4;
  const int chb  = (q4 & 1) << 3;

  // XCD swizzle: 2 bh per XCD
  const int orig = ((blockIdx.x & 7) << 7) + (blockIdx.x >> 3);
  const int bh = orig >> 6;
  const int i0 = (orig & 63) << 6;
  const int b = bh >> 2, h = bh & 3;

  // Q B-frags: lane col n=i_, k=8q4+e; k<16 -> Qhi plane, k>=16 -> Qlo plane,
  // channel chb+e. One 16B load per g.
  const unsigned short* qpb =
      qsplit + ((size_t)(q4 >> 1) << 20) + ((size_t)bh << 16) + chb;
  s8v BQ[4];
#pragma unroll
  for (int g = 0; g < 4; ++g) {
    BQ[g] = *(const s8v*)(qpb + ((size_t)(i0 + (g << 4) + i_) << 4));
  }

  s8v ones;
#pragma unroll
  for (int e = 0; e < 8; ++e) ones[e] = (short)0x3F80;  // bf16 1.0

  f32x4 acc[4], accl[4];
#pragma unroll
  for (int g = 0; g < 4; ++g) {
    acc[g] = (f32x4){0.f, 0.f, 0.f, 0.f};
    accl[g] = (f32x4){0.f, 0.f, 0.f, 0.f};
  }

  const unsigned short* vpb = vb + (((size_t)(b * 64 + h * 16 + i_)) << 12);
  const unsigned short* kpb = kT + ((size_t)bh << 16);

  for (int t = 0; t < 16; ++t) {
    const int ja = (w << 10) + (t << 6);
    const int jbB = ja + 32;
    // Two independent 32-j load groups (A at ja, B at ja+32)
    s8v AVa, AVb;
    {
      struct { uint2 a, b; } pa, pb;
      pa.a = *(const uint2*)(vpb + ja + (q4 << 2));
      pa.b = *(const uint2*)(vpb + ja + 16 + (q4 << 2));
      pb.a = *(const uint2*)(vpb + jbB + (q4 << 2));
      pb.b = *(const uint2*)(vpb + jbB + 16 + (q4 << 2));
      AVa = __builtin_bit_cast(s8v, pa);
      AVb = __builtin_bit_cast(s8v, pb);
    }
    s8v AK0a = *(const s8v*)(kpb + (((size_t)(ja + i_)) << 4) + chb);
    s8v AK1a = *(const s8v*)(kpb + (((size_t)(ja + 16 + i_)) << 4) + chb);
    s8v AK0b = *(const s8v*)(kpb + (((size_t)(jbB + i_)) << 4) + chb);
    s8v AK1b = *(const s8v*)(kpb + (((size_t)(jbB + 16 + i_)) << 4) + chb);

#pragma unroll
    for (int g = 0; g < 4; ++g) {
      f32x4 z = {0.f, 0.f, 0.f, 0.f};
      f32x4 s0 = __builtin_amdgcn_mfma_f32_16x16x32_bf16(AK0a, BQ[g], z, 0, 0, 0);
      f32x4 s1 = __builtin_amdgcn_mfma_f32_16x16x32_bf16(AK1a, BQ[g], z, 0, 0, 0);
      f32x4 s2 = __builtin_amdgcn_mfma_f32_16x16x32_bf16(AK0b, BQ[g], z, 0, 0, 0);
      f32x4 s3 = __builtin_amdgcn_mfma_f32_16x16x32_bf16(AK1b, BQ[g], z, 0, 0, 0);
      float pa0 = __builtin_amdgcn_exp2f(s0[0]);
      float pa1 = __builtin_amdgcn_exp2f(s0[1]);
      float pa2 = __builtin_amdgcn_exp2f(s0[2]);
      float pa3 = __builtin_amdgcn_exp2f(s0[3]);
      float pa4 = __builtin_amdgcn_exp2f(s1[0]);
      float pa5 = __builtin_amdgcn_exp2f(s1[1]);
      float pa6 = __builtin_amdgcn_exp2f(s1[2]);
      float pa7 = __builtin_amdgcn_exp2f(s1[3]);
      float pb0 = __builtin_amdgcn_exp2f(s2[0]);
      float pb1 = __builtin_amdgcn_exp2f(s2[1]);
      float pb2 = __builtin_amdgcn_exp2f(s2[2]);
      float pb3 = __builtin_amdgcn_exp2f(s2[3]);
      float pb4 = __builtin_amdgcn_exp2f(s3[0]);
      float pb5 = __builtin_amdgcn_exp2f(s3[1]);
      float pb6 = __builtin_amdgcn_exp2f(s3[2]);
      float pb7 = __builtin_amdgcn_exp2f(s3[3]);
      struct { unsigned x, y, z, w; } ua, ub;
      ua.x = cvtpk(pa0, pa1); ua.y = cvtpk(pa2, pa3);
      ua.z = cvtpk(pa4, pa5); ua.w = cvtpk(pa6, pa7);
      ub.x = cvtpk(pb0, pb1); ub.y = cvtpk(pb2, pb3);
      ub.z = cvtpk(pb4, pb5); ub.w = cvtpk(pb6, pb7);
      s8v PA = __builtin_bit_cast(s8v, ua);
      s8v PB = __builtin_bit_cast(s8v, ub);
      acc[g]  = __builtin_amdgcn_mfma_f32_16x16x32_bf16(AVa, PA, acc[g], 0, 0, 0);
      acc[g]  = __builtin_amdgcn_mfma_f32_16x16x32_bf16(AVb, PB, acc[g], 0, 0, 0);
      accl[g] = __builtin_amdgcn_mfma_f32_16x16x32_bf16(ones, PA, accl[g], 0, 0, 0);
      accl[g] = __builtin_amdgcn_mfma_f32_16x16x32_bf16(ones, PB, accl[g], 0, 0, 0);
    }
  }

  // per-wave results -> LDS merge across the 4 j-slices (pure sums;
  // accl[g][0] is the per-query l, identical on all 4 lanes of a query)
#pragma unroll
  for (int g = 0; g < 4; ++g) {
    int iq = (g << 4) + i_;
    if (q4 == 0) red[w][iq][0] = accl[g][0];
    red[w][iq][1 + (q4 << 2) + 0] = acc[g][0];
    red[w][iq][1 + (q4 << 2) + 1] = acc[g][1];
    red[w][iq][1 + (q4 << 2) + 2] = acc[g][2];
    red[w][iq][1 + (q4 << 2) + 3] = acc[g][3];
  }
  __syncthreads();

  {
    int iq = tid & 63, quad = tid >> 6;
    float L = (red[0][iq][0] + red[1][iq][0]) + (red[2][iq][0] + red[3][iq][0]);
    float o0 = 0.f, o1 = 0.f, o2 = 0.f, o3 = 0.f;
#pragma unroll
    for (int s = 0; s < 4; ++s) {
      o0 += red[s][iq][1 + (quad << 2) + 0];
      o1 += red[s][iq][1 + (quad << 2) + 1];
      o2 += red[s][iq][1 + (quad << 2) + 2];
      o3 += red[s][iq][1 + (quad << 2) + 3];
    }
    float inv = 1.0f / L;
    float4 o = { o0 * inv, o1 * inv, o2 * inv, o3 * inv };
    *(float4*)&ao[((((size_t)bh << 12) + i0 + iq) << 4) + (quad << 2)] = o;
  }
}

// 32-pixel tiles -> grid 512 -> higher residency than the 1-block/CU original.
__global__ __launch_bounds__(256) void out_proj(
    const float* __restrict__ a, const float* __restrict__ wp,
    const float* __restrict__ bp, float* __restrict__ out) {
  __shared__ __align__(16) float as[64][32];
  __shared__ float wps[64][65];
  int t = threadIdx.x;
  int b = blockIdx.x >> 7;
  int px0 = (blockIdx.x & 127) << 5;
#pragma unroll
  for (int kk = 0; kk < 16; kk++) {
    int idx = kk * 256 + t;
    int o = idx >> 6, c2 = idx & 63;
    wps[c2][o] = wp[idx];
  }
#pragma unroll
  for (int kk = 0; kk < 8; kk++) {
    int idx = kk * 256 + t;
    int c = idx >> 5, px = idx & 31;
    as[c][px] = a[((size_t)b << 18) + ((size_t)c << 12) + px0 + px];
  }
  __syncthreads();

  int o = t & 63;
  int pw = (t >> 6) << 3;
  float acc[8];
#pragma unroll
  for (int p = 0; p < 8; p++) acc[p] = 0.f;
  for (int c = 0; c < 64; c++) {
    float wv = wps[c][o];
    float4 x0 = *reinterpret_cast<const float4*>(&as[c][pw]);
    float4 x1 = *reinterpret_cast<const float4*>(&as[c][pw + 4]);
    float xr[8] = { x0.x, x0.y, x0.z, x0.w, x1.x, x1.y, x1.z, x1.w };
#pragma unroll
    for (int p = 0; p < 8; p++) acc[p] += wv * xr[p];
  }
  float bv = bp[o];
  float* dst = out + ((size_t)(b * 64 + o) << 12) + px0 + pw;
  float4 v0 = { acc[0] + bv, acc[1] + bv, acc[2] + bv, acc[3] + bv };
  float4 v1 = { acc[4] + bv, acc[5] + bv, acc[6] + bv, acc[7] + bv };
  reinterpret_cast<float4*>(dst)[0] = v0;
  reinterpret_cast<float4*>(dst)[1] = v1;
}

extern "C" void kernel_launch(void* const* d_in, const int* in_sizes, int n_in,
                              void* d_out, int out_size, void* d_ws, size_t ws_size,
                              hipStream_t stream) {
  (void)in_sizes; (void)n_in; (void)out_size; (void)ws_size;
  const float* x  = (const float*)d_in[0];
  const float* wq = (const float*)d_in[1];
  const float* bq = (const float*)d_in[2];
  const float* wk = (const float*)d_in[3];
  const float* bk = (const float*)d_in[4];
  const float* wv = (const float*)d_in[5];
  const float* bv = (const float*)d_in[6];
  const float* wp = (const float*)d_in[7];
  const float* bp = (const float*)d_in[8];

  char* ws = (char*)d_ws;
  unsigned short* qsplit = (unsigned short*)ws;              // 4MB (hi+lo planes)
  unsigned short* kT = (unsigned short*)(ws + (4u << 20));   // 2MB bf16
  unsigned short* vT = (unsigned short*)(ws + (6u << 20));   // 2MB bf16
  float* ao = (float*)(ws + (8u << 20));                     // 4MB f32

  qkv_proj<<<512, 256, 0, stream>>>(x, wq, bq, wk, bk, wv, bv, qsplit, kT, vT);
  attn_mfma<<<1024, 256, 0, stream>>>(qsplit, kT, vT, ao);
  out_proj<<<512, 256, 0, stream>>>(ao, wp, bp, (float*)d_out);
}